// Round 10
// baseline (49.374 us; speedup 1.0000x reference)
//
#include <hip/hip_runtime.h>
#include <hip/hip_bf16.h>

typedef __attribute__((ext_vector_type(8))) short short8;
typedef __attribute__((ext_vector_type(4))) float f32x4;

#define MFMA(a, b, c) __builtin_amdgcn_mfma_f32_16x16x32_bf16((a), (b), (c), 0, 0, 0)

// packed pair: low 16 = bf16(a), high 16 = bf16(b) -> v_cvt_pk_bf16_f32
__device__ __forceinline__ unsigned int f2bf2(float a, float b) {
  __hip_bfloat162 h2 = __float22bfloat162_rn(make_float2(a, b));
  union { __hip_bfloat162 h; unsigned int u; } cv; cv.h = h2;
  return cv.u;
}

__device__ __forceinline__ float bfhi2f(unsigned int u) {  // high 16 bits as bf16
  union { unsigned int u; float f; } c; c.u = u & 0xffff0000u; return c.f;
}
__device__ __forceinline__ float bflo2f(unsigned int u) {  // low 16 bits as bf16
  union { unsigned int u; float f; } c; c.u = u << 16; return c.f;
}

// ---------------------------------------------------------------------------
// k0: W -> W3t bf16 in FRAG-LINEAR layout: 16B chunk index
//   j = (kstep*12 + ct)*64 + lane,  lane=(g*16+q)
// holding W^T[n=16ct'+q][k=32*kstep+8g .. +7]  (ct': Q ct 0-3, K 4-7, V 8-11)
// ---------------------------------------------------------------------------
__global__ void wconv_kernel(const float* __restrict__ Wq, const float* __restrict__ Wk,
                             const float* __restrict__ Wv, unsigned short* __restrict__ W3t) {
  int j = blockIdx.x * 128 + threadIdx.x;  // 0..9215 (uint4 chunks)
  int s = j / 768;
  int r = j - s * 768;
  int ct = r >> 6, l = r & 63, g = l >> 4, q = l & 15;
  const float* src = (ct < 4) ? Wq : ((ct < 8) ? Wk : Wv);
  int col = 16 * (ct & 3) + q;
  int k = 32 * s + 8 * g;
  float e[8];
#pragma unroll
  for (int i = 0; i < 8; ++i) e[i] = src[(k + i) * 64 + col];
  uint4 u;
  u.x = f2bf2(e[0], e[1]); u.y = f2bf2(e[2], e[3]);
  u.z = f2bf2(e[4], e[5]); u.w = f2bf2(e[6], e[7]);
  *(uint4*)&W3t[j * 8] = u;
}

// ---------------------------------------------------------------------------
// Fused per-batch kernel. 1024 threads = 16 waves (4/SIMD), 1 block/CU.
// Dynamic LDS 147456 B (73728 ush):
//   proj-phase: Wf frag-linear, whole W (9216 x 16B chunks)
//   reduce-phase (overlays Wf): partial scratch [8][24][64] uint2 = 98304 B
//   attn-phase (overlays all): Ql [256][72] @0 | Kl @18432 | Vl [64][264] @36864
//                              Pb 16 x [16][40] @53760 (ends 64000 ush)
// Proj K-SPLIT (LDS-BW lever): wave pair (w, w+8) shares rows 32w..32w+31;
//   wave w: k 0..191, wave w+8: k 192..383. Each wave: 6 steps x 12 B-frags,
//   each B-frag feeds 2 MFMAs (2 A-rows) -> LDS B-traffic HALVED vs R9;
//   every x byte read exactly once per block (no duplicate streams).
//   Partials merged via bf16-packed LDS scratch (waves 8-15 write, 0-7 add).
// Attn: swapped QK^T (scores lane-local per q-row), online softmax, tile t=w.
// ---------------------------------------------------------------------------
__global__ __launch_bounds__(1024) void fused_kernel(
    const float* __restrict__ x, const unsigned short* __restrict__ W3t,
    float* __restrict__ out) {
  extern __shared__ unsigned short sm[];
  unsigned short* Ql = sm;
  unsigned short* Kl = sm + 18432;
  unsigned short* Vl = sm + 36864;

  const int tid = threadIdx.x;  // 0..1023
  const int w = tid >> 6, lane = tid & 63, g = lane >> 4, q = lane & 15;
  const int half = w >> 3;      // k-half: 0 -> k[0,192), 1 -> k[192,384)
  const int wr = w & 7;         // row-group: rows 32*wr .. 32*wr+31
  const int b = blockIdx.x;
  const float* xb = x + (long)b * 98304;

  // ---- stage whole W into LDS (frag-linear; coalesced; conflict-free) ----
#pragma unroll
  for (int i = 0; i < 9; ++i) {
    int idx = tid + i * 1024;  // uint4 chunk index
    *(uint4*)&sm[idx * 8] = *(const uint4*)&W3t[idx * 8];
  }

  f32x4 acc0[12], acc1[12];  // rows (32wr + q) / (32wr + 16 + q), this k-half
  const f32x4 zf = {0.f, 0.f, 0.f, 0.f};
#pragma unroll
  for (int j = 0; j < 12; ++j) { acc0[j] = zf; acc1[j] = zf; }

  // x sources: lane (q,g) owns rows 32wr+q and 32wr+16+q, k = 192*half + 32*ks + 8g
  const float* xrA = xb + (32 * wr + q) * 384 + 192 * half + 8 * g;
  const float* xrB = xrA + 16 * 384;
  float4 A0[2], A1[2], B0[2], B1[2];  // [parity] - depth-2 prefetch
#pragma unroll
  for (int p = 0; p < 2; ++p) {
    A0[p] = *(const float4*)&xrA[32 * p];
    A1[p] = *(const float4*)&xrA[32 * p + 4];
    B0[p] = *(const float4*)&xrB[32 * p];
    B1[p] = *(const float4*)&xrB[32 * p + 4];
  }

  __syncthreads();  // Wf staged

  // ---- proj main loop: 6 x BK=32 (this wave's k-half), no barriers ----
#pragma unroll
  for (int ks = 0; ks < 6; ++ks) {
    const int p = ks & 1;  // constant after unroll
    uint4 auA, auB;
    auA.x = f2bf2(A0[p].x, A0[p].y); auA.y = f2bf2(A0[p].z, A0[p].w);
    auA.z = f2bf2(A1[p].x, A1[p].y); auA.w = f2bf2(A1[p].z, A1[p].w);
    auB.x = f2bf2(B0[p].x, B0[p].y); auB.y = f2bf2(B0[p].z, B0[p].w);
    auB.z = f2bf2(B1[p].x, B1[p].y); auB.w = f2bf2(B1[p].z, B1[p].w);
    union { uint4 u; short8 s8; } avA, avB;
    avA.u = auA; avB.u = auB;
    if (ks < 4) {  // refill parity slot with step ks+2
      A0[p] = *(const float4*)&xrA[32 * (ks + 2)];
      A1[p] = *(const float4*)&xrA[32 * (ks + 2) + 4];
      B0[p] = *(const float4*)&xrB[32 * (ks + 2)];
      B1[p] = *(const float4*)&xrB[32 * (ks + 2) + 4];
    }
    const unsigned short* wbase = sm + (6 * half + ks) * 6144 + lane * 8;
#pragma unroll
    for (int ct = 0; ct < 12; ++ct) {
      short8 bfr = *(const short8*)&wbase[ct * 512];  // read once, feed 2 MFMAs
      acc0[ct] = MFMA(avA.s8, bfr, acc0[ct]);
      acc1[ct] = MFMA(avB.s8, bfr, acc1[ct]);
    }
  }
  __syncthreads();  // all waves done reading Wf; scratch may overlay

  // ---- K-half reduce: waves 8-15 write bf16-packed partials to scratch ----
  // scratch layout: uint2 @ ush offset ((wr*24 + slot)*64 + lane)*4, 98304 B
  if (half == 1) {
#pragma unroll
    for (int rt = 0; rt < 2; ++rt) {
#pragma unroll
      for (int ct = 0; ct < 12; ++ct) {
        const f32x4 a = rt ? acc1[ct] : acc0[ct];
        uint2 pk;
        pk.x = f2bf2(a[0], a[1]);
        pk.y = f2bf2(a[2], a[3]);
        *(uint2*)&sm[((wr * 24 + rt * 12 + ct) * 64 + lane) * 4] = pk;
      }
    }
  }
  __syncthreads();
  if (half == 0) {
#pragma unroll
    for (int rt = 0; rt < 2; ++rt) {
#pragma unroll
      for (int ct = 0; ct < 12; ++ct) {
        uint2 pk = *(const uint2*)&sm[((wr * 24 + rt * 12 + ct) * 64 + lane) * 4];
        f32x4& a = rt ? acc1[ct] : acc0[ct];
        a[0] += bflo2f(pk.x); a[1] += bfhi2f(pk.x);
        a[2] += bflo2f(pk.y); a[3] += bfhi2f(pk.y);
      }
    }
  }
  __syncthreads();  // scratch reads done; QKV writes may overlay scratch

  // ---- proj epilogue (waves 0-7): QKV -> LDS (col=lane&15, row=4g+reg) ----
  if (half == 0) {
#pragma unroll
    for (int rt = 0; rt < 2; ++rt) {
      const int mb = 32 * wr + 16 * rt + 4 * g;  // within-batch row base
#pragma unroll
      for (int ct = 0; ct < 12; ++ct) {
        const f32x4 a = rt ? acc1[ct] : acc0[ct];
        int c = 16 * ct + q;
        unsigned int p01 = f2bf2(a[0], a[1]);
        unsigned int p23 = f2bf2(a[2], a[3]);
        unsigned short h0 = (unsigned short)p01, h1 = (unsigned short)(p01 >> 16);
        unsigned short h2 = (unsigned short)p23, h3 = (unsigned short)(p23 >> 16);
        if (ct < 4) {
          Ql[(mb + 0) * 72 + c] = h0; Ql[(mb + 1) * 72 + c] = h1;
          Ql[(mb + 2) * 72 + c] = h2; Ql[(mb + 3) * 72 + c] = h3;
        } else if (ct < 8) {
          int cc = c - 64;
          Kl[(mb + 0) * 72 + cc] = h0; Kl[(mb + 1) * 72 + cc] = h1;
          Kl[(mb + 2) * 72 + cc] = h2; Kl[(mb + 3) * 72 + cc] = h3;
        } else {
          int hh = c - 128;
          uint2 pk; pk.x = p01; pk.y = p23;
          *(uint2*)&Vl[hh * 264 + mb] = pk;  // V^T[h][tok..tok+3]
        }
      }
    }
  }
  __syncthreads();

  // ---- attention: wave w owns row-tile t = w; swapped QK^T + online SM ----
  unsigned short* Pb = sm + 53760 + w * 640;  // per-wave [16][40] P buffer
  const float SCL = 0.125f * 1.4426950408889634f;  // H^-0.5 * log2(e)
  const int t = w;

  // Q as B-operand: lane (q,g) holds Q[16t+q][8g..8g+7]
  short8 aq0 = *(const short8*)&Ql[(16 * t + q) * 72 + g * 8];
  short8 aq1 = *(const short8*)&Ql[(16 * t + q) * 72 + 32 + g * 8];

  f32x4 o[4];
#pragma unroll
  for (int ct = 0; ct < 4; ++ct) o[ct] = zf;
  float m = -1e30f;   // running max for q-row 16t+q
  float lsum = 0.f;   // per-lane partial row-sum for q-row 16t+q

  const int KS = (t >> 1) + 1;  // runtime trip count, wave-uniform
  for (int ks = 0; ks < KS; ++ks) {
    const int j0 = 2 * ks, j1 = 2 * ks + 1;
    const bool has1 = (j1 <= t);
    // K as A-operand: D[row=4g+jr][col=q] = S[K-token 16j+4g+jr][Q-row 16t+q]
    short8 ka0 = *(const short8*)&Kl[(16 * j0 + q) * 72 + g * 8];
    short8 ka1 = *(const short8*)&Kl[(16 * j0 + q) * 72 + 32 + g * 8];
    f32x4 s0 = MFMA(ka0, aq0, zf);
    s0 = MFMA(ka1, aq1, s0);
    f32x4 s1 = zf;
    if (has1) {
      short8 kb0 = *(const short8*)&Kl[(16 * j1 + q) * 72 + g * 8];
      short8 kb1 = *(const short8*)&Kl[(16 * j1 + q) * 72 + 32 + g * 8];
      s1 = MFMA(kb0, aq0, zf);
      s1 = MFMA(kb1, aq1, s1);
    }
    float v[8];
#pragma unroll
    for (int jr = 0; jr < 4; ++jr) {
      float aa = s0[jr] * SCL;
      if (j0 == t && 4 * g + jr > q) aa = -1e30f;  // causal (diag tile)
      v[jr] = aa;
      float c = has1 ? s1[jr] * SCL : -1e30f;
      if (has1 && j1 == t && 4 * g + jr > q) c = -1e30f;
      v[4 + jr] = c;
    }
    float mloc = fmaxf(fmaxf(fmaxf(v[0], v[1]), fmaxf(v[2], v[3])),
                       fmaxf(fmaxf(v[4], v[5]), fmaxf(v[6], v[7])));
    mloc = fmaxf(mloc, __shfl_xor(mloc, 16));
    mloc = fmaxf(mloc, __shfl_xor(mloc, 32));
    float mnew = fmaxf(m, mloc);
    float f = exp2f(m - mnew);  // rescale factor for q-row q (this lane's row)
    m = mnew;
    float p[8];
    float ls = 0.f;
#pragma unroll
    for (int i = 0; i < 8; ++i) { p[i] = exp2f(v[i] - mnew); ls += p[i]; }
    lsum = lsum * f + ls;
    // o[ct][jr] accumulates Q-row 4g+jr -> fetch THAT row's factor (lane 4g+jr)
#pragma unroll
    for (int jr = 0; jr < 4; ++jr) {
      float fr = __shfl(f, 4 * g + jr);
      o[0][jr] *= fr; o[1][jr] *= fr; o[2][jr] *= fr; o[3][jr] *= fr;
    }
    // P store (row q, cols 4g..4g+3 of each 16-tile) then transposed read
    uint2 pa; pa.x = f2bf2(p[0], p[1]); pa.y = f2bf2(p[2], p[3]);
    *(uint2*)&Pb[q * 40 + 4 * g] = pa;
    uint2 pc; pc.x = f2bf2(p[4], p[5]); pc.y = f2bf2(p[6], p[7]);
    *(uint2*)&Pb[q * 40 + 16 + 4 * g] = pc;
    short8 ap = *(const short8*)&Pb[q * 40 + g * 8];
#pragma unroll
    for (int ct = 0; ct < 4; ++ct) {
      short8 bv = *(const short8*)&Vl[(16 * ct + q) * 264 + ks * 32 + g * 8];
      o[ct] = MFMA(ap, bv, o[ct]);
    }
  }

  // final row-sum: fold g-partials (row q), then fetch row 4g+jr's sum
  lsum += __shfl_xor(lsum, 16);
  lsum += __shfl_xor(lsum, 32);
  float linv[4];
#pragma unroll
  for (int jr = 0; jr < 4; ++jr) linv[jr] = 1.0f / __shfl(lsum, 4 * g + jr);

  const long rowbase = (long)b * 256 + 16 * t;
#pragma unroll
  for (int jr = 0; jr < 4; ++jr) {
#pragma unroll
    for (int ct = 0; ct < 4; ++ct) {
      out[(rowbase + 4 * g + jr) * 64 + 16 * ct + q] = o[ct][jr] * linv[jr];
    }
  }
}

// ---------------------------------------------------------------------------
extern "C" void kernel_launch(void* const* d_in, const int* in_sizes, int n_in,
                              void* d_out, int out_size, void* d_ws, size_t ws_size,
                              hipStream_t stream) {
  const float* x  = (const float*)d_in[0];
  const float* Wq = (const float*)d_in[1];
  const float* Wk = (const float*)d_in[2];
  const float* Wv = (const float*)d_in[3];
  float* out = (float*)d_out;

  unsigned short* W3t = (unsigned short*)d_ws;  // 147,456 B

  hipFuncSetAttribute((const void*)fused_kernel,
                      hipFuncAttributeMaxDynamicSharedMemorySize, 147456);

  wconv_kernel<<<72, 128, 0, stream>>>(Wq, Wk, Wv, W3t);
  fused_kernel<<<256, 1024, 147456, stream>>>(x, W3t, out);
}

// Round 11
// 39.483 us; speedup vs baseline: 1.2505x; 1.2505x over previous
//
#include <hip/hip_runtime.h>
#include <hip/hip_bf16.h>

typedef __attribute__((ext_vector_type(8))) short short8;
typedef __attribute__((ext_vector_type(4))) float f32x4;
typedef __attribute__((ext_vector_type(16))) float f32x16;

#define MFMA16(a, b, c) __builtin_amdgcn_mfma_f32_16x16x32_bf16((a), (b), (c), 0, 0, 0)
#define MFMA32(a, b, c) __builtin_amdgcn_mfma_f32_32x32x16_bf16((a), (b), (c), 0, 0, 0)

__device__ __forceinline__ unsigned short f2bf(float f) {
  union { float f; unsigned int u; } v; v.f = f;
  unsigned int u = v.u;
  unsigned int r = u + 0x7FFFu + ((u >> 16) & 1u);  // RNE
  return (unsigned short)(r >> 16);
}

// packed pair: low 16 = bf16(a), high 16 = bf16(b) -> v_cvt_pk_bf16_f32
__device__ __forceinline__ unsigned int f2bf2(float a, float b) {
  __hip_bfloat162 h2 = __float22bfloat162_rn(make_float2(a, b));
  union { __hip_bfloat162 h; unsigned int u; } cv; cv.h = h2;
  return cv.u;
}

// ---------------------------------------------------------------------------
// k0: W -> W3t bf16 frag-linear for 32x32x16 MFMA B-frags. 16B chunk index
//   j = (s2*6 + c)*64 + l,  s2 = k-substep (k16) 0..23, c = col-tile(32) 0..5
// lane l holds W^T[col = 32c + (l&31)][k = 16*s2 + 8*(l>>5) + 0..7]
// -> fused B-frag ds_read_b128 is lane-unit-stride (conflict-free).
// ---------------------------------------------------------------------------
__global__ void wconv_kernel(const float* __restrict__ Wq, const float* __restrict__ Wk,
                             const float* __restrict__ Wv, unsigned short* __restrict__ W3t) {
  int j = blockIdx.x * 128 + threadIdx.x;  // 0..9215 (uint4 chunks)
  int s2 = j / 384;
  int r = j - s2 * 384;
  int c = r >> 6, l = r & 63;
  int col = 32 * c + (l & 31);             // 0..191 across Q|K|V
  int k = 16 * s2 + 8 * (l >> 5);
  const float* src = (col < 64) ? Wq : ((col < 128) ? Wk : Wv);
  int sc = col & 63;
  float e[8];
#pragma unroll
  for (int i = 0; i < 8; ++i) e[i] = src[(k + i) * 64 + sc];
  uint4 u;
  u.x = f2bf2(e[0], e[1]); u.y = f2bf2(e[2], e[3]);
  u.z = f2bf2(e[4], e[5]); u.w = f2bf2(e[6], e[7]);
  *(uint4*)&W3t[j * 8] = u;
}

// ---------------------------------------------------------------------------
// Fused per-batch kernel. 512 threads = 8 waves (2/SIMD, 256-VGPR budget
// per wave -> 96-reg acc CANNOT spill). Dynamic LDS 147456 B:
//   proj: Wf frag-linear (whole W)
//   attn (overlays Wf): Ql [256][72] @0 | Kl @18432 | Vl [64][264] @36864
//                       Pb 8 x [16][40] @53760
// Proj: 32x32x16 MFMA. Wave w: rows 32w..32w+31 x all 192 cols (6 col-tiles,
//   acc 6 x f32x16 = 96 VGPR). Per BK=32 step: 12 ds_read_b128 feed 12 MFMAs
//   covering 32 rows -> LDS traffic HALVED vs 16x16 (1.15 MB/CU), x bytes
//   read exactly once (no duplication), no barriers, depth-1 x prefetch.
// Attn: 2 tiles/wave {w, 15-w}; swapped QK^T, online softmax (R6 body).
// ---------------------------------------------------------------------------
__global__ __launch_bounds__(512) void fused_kernel(
    const float* __restrict__ x, const unsigned short* __restrict__ W3t,
    float* __restrict__ out) {
  extern __shared__ unsigned short sm[];
  unsigned short* Ql = sm;
  unsigned short* Kl = sm + 18432;
  unsigned short* Vl = sm + 36864;

  const int tid = threadIdx.x;  // 0..511
  const int w = tid >> 6, lane = tid & 63, g = lane >> 4, q = lane & 15;
  const int l31 = lane & 31, h = lane >> 5;
  const int b = blockIdx.x;
  const float* xb = x + (long)b * 98304;

  // ---- stage whole W into LDS (frag-linear; coalesced; conflict-free) ----
#pragma unroll
  for (int i = 0; i < 18; ++i) {
    int idx = tid + i * 512;  // uint4 chunk index 0..9215
    *(uint4*)&sm[idx * 8] = *(const uint4*)&W3t[idx * 8];
  }

  f32x16 acc[6];
#pragma unroll
  for (int j = 0; j < 6; ++j)
#pragma unroll
    for (int r = 0; r < 16; ++r) acc[j][r] = 0.f;

  // x source: lane owns row 32w + l31; substep elems at 8h / 16+8h (+32*ks)
  const float* xrow = xb + (32 * w + l31) * 384 + 8 * h;
  float4 c0 = *(const float4*)&xrow[0];
  float4 c1 = *(const float4*)&xrow[4];
  float4 c2 = *(const float4*)&xrow[16];
  float4 c3 = *(const float4*)&xrow[20];

  __syncthreads();  // Wf staged (x prologue loads in flight)

  // ---- proj main loop: 12 x BK=32, free-running, no barriers ----
#pragma unroll
  for (int ks = 0; ks < 12; ++ks) {
    float4 n0, n1, n2, n3;
    if (ks < 11) {
      n0 = *(const float4*)&xrow[32 * (ks + 1)];
      n1 = *(const float4*)&xrow[32 * (ks + 1) + 4];
      n2 = *(const float4*)&xrow[32 * (ks + 1) + 16];
      n3 = *(const float4*)&xrow[32 * (ks + 1) + 20];
    }
    uint4 a0u, a1u;
    a0u.x = f2bf2(c0.x, c0.y); a0u.y = f2bf2(c0.z, c0.w);
    a0u.z = f2bf2(c1.x, c1.y); a0u.w = f2bf2(c1.z, c1.w);
    a1u.x = f2bf2(c2.x, c2.y); a1u.y = f2bf2(c2.z, c2.w);
    a1u.z = f2bf2(c3.x, c3.y); a1u.w = f2bf2(c3.z, c3.w);
    union { uint4 u; short8 s8; } av0, av1;
    av0.u = a0u; av1.u = a1u;
    const unsigned short* base = sm + (2 * ks) * 3072 + lane * 8;
#pragma unroll
    for (int ct = 0; ct < 6; ++ct) {
      short8 b0 = *(const short8*)&base[ct * 512];
      acc[ct] = MFMA32(av0.s8, b0, acc[ct]);
      short8 b1 = *(const short8*)&base[3072 + ct * 512];
      acc[ct] = MFMA32(av1.s8, b1, acc[ct]);
    }
    if (ks < 11) { c0 = n0; c1 = n1; c2 = n2; c3 = n3; }
  }
  __syncthreads();  // all waves done reading Wf; safe to overlay

  // ---- proj epilogue: QKV -> LDS
  // D layout (32x32): col = 32ct + l31, row_local = (r&3) + 8*(r>>2) + 4h ----
#pragma unroll
  for (int ct = 0; ct < 6; ++ct) {
    const int C = 32 * ct + l31;
    if (ct < 2) {  // Q cols 0..63
#pragma unroll
      for (int r = 0; r < 16; ++r) {
        int row = 32 * w + (r & 3) + 8 * (r >> 2) + 4 * h;
        Ql[row * 72 + C] = f2bf(acc[ct][r]);
      }
    } else if (ct < 4) {  // K cols 64..127
      const int cc = C - 64;
#pragma unroll
      for (int r = 0; r < 16; ++r) {
        int row = 32 * w + (r & 3) + 8 * (r >> 2) + 4 * h;
        Kl[row * 72 + cc] = f2bf(acc[ct][r]);
      }
    } else {  // V cols 128..191 -> V^T[h][tok], 4-token packs
      const int hh = C - 128;
#pragma unroll
      for (int rq = 0; rq < 4; ++rq) {
        int mb = 32 * w + 8 * rq + 4 * h;  // 4 consecutive tokens
        uint2 pk;
        pk.x = f2bf2(acc[ct][4 * rq + 0], acc[ct][4 * rq + 1]);
        pk.y = f2bf2(acc[ct][4 * rq + 2], acc[ct][4 * rq + 3]);
        *(uint2*)&Vl[hh * 264 + mb] = pk;
      }
    }
  }
  __syncthreads();

  // ---- attention: wave w owns tiles {w, 15-w}; swapped QK^T + online SM ----
  unsigned short* Pb = sm + 53760 + w * 640;  // per-wave [16][40] P buffer
  const float SCL = 0.125f * 1.4426950408889634f;  // H^-0.5 * log2(e)
  const f32x4 zf = {0.f, 0.f, 0.f, 0.f};

#pragma unroll
  for (int ti = 0; ti < 2; ++ti) {
    const int t = ti ? (15 - w) : w;

    // Q as B-operand: lane (q,g) holds Q[16t+q][8g..8g+7]
    short8 aq0 = *(const short8*)&Ql[(16 * t + q) * 72 + g * 8];
    short8 aq1 = *(const short8*)&Ql[(16 * t + q) * 72 + 32 + g * 8];

    f32x4 o[4];
#pragma unroll
    for (int ct = 0; ct < 4; ++ct) o[ct] = zf;
    float m = -1e30f;
    float lsum = 0.f;

    const int KS = (t >> 1) + 1;  // wave-uniform trip count
    for (int ks = 0; ks < KS; ++ks) {
      const int j0 = 2 * ks, j1 = 2 * ks + 1;
      const bool has1 = (j1 <= t);
      short8 ka0 = *(const short8*)&Kl[(16 * j0 + q) * 72 + g * 8];
      short8 ka1 = *(const short8*)&Kl[(16 * j0 + q) * 72 + 32 + g * 8];
      f32x4 s0 = MFMA16(ka0, aq0, zf);
      s0 = MFMA16(ka1, aq1, s0);
      f32x4 s1 = zf;
      if (has1) {
        short8 kb0 = *(const short8*)&Kl[(16 * j1 + q) * 72 + g * 8];
        short8 kb1 = *(const short8*)&Kl[(16 * j1 + q) * 72 + 32 + g * 8];
        s1 = MFMA16(kb0, aq0, zf);
        s1 = MFMA16(kb1, aq1, s1);
      }
      float v[8];
#pragma unroll
      for (int jr = 0; jr < 4; ++jr) {
        float aa = s0[jr] * SCL;
        if (j0 == t && 4 * g + jr > q) aa = -1e30f;  // causal (diag tile)
        v[jr] = aa;
        float cc = has1 ? s1[jr] * SCL : -1e30f;
        if (has1 && j1 == t && 4 * g + jr > q) cc = -1e30f;
        v[4 + jr] = cc;
      }
      float mloc = fmaxf(fmaxf(fmaxf(v[0], v[1]), fmaxf(v[2], v[3])),
                         fmaxf(fmaxf(v[4], v[5]), fmaxf(v[6], v[7])));
      mloc = fmaxf(mloc, __shfl_xor(mloc, 16));
      mloc = fmaxf(mloc, __shfl_xor(mloc, 32));
      float mnew = fmaxf(m, mloc);
      float f = exp2f(m - mnew);  // factor for q-row q (this lane's row)
      m = mnew;
      float p[8];
      float ls = 0.f;
#pragma unroll
      for (int i = 0; i < 8; ++i) { p[i] = exp2f(v[i] - mnew); ls += p[i]; }
      lsum = lsum * f + ls;
      // o[ct][jr] accumulates Q-row 4g+jr -> fetch that row's factor
#pragma unroll
      for (int jr = 0; jr < 4; ++jr) {
        float fr = __shfl(f, 4 * g + jr);
        o[0][jr] *= fr; o[1][jr] *= fr; o[2][jr] *= fr; o[3][jr] *= fr;
      }
      // P store (row q, cols 4g..4g+3 of each 16-tile) then transposed read
      uint2 pa; pa.x = f2bf2(p[0], p[1]); pa.y = f2bf2(p[2], p[3]);
      *(uint2*)&Pb[q * 40 + 4 * g] = pa;
      uint2 pc; pc.x = f2bf2(p[4], p[5]); pc.y = f2bf2(p[6], p[7]);
      *(uint2*)&Pb[q * 40 + 16 + 4 * g] = pc;
      short8 ap = *(const short8*)&Pb[q * 40 + g * 8];
#pragma unroll
      for (int ct = 0; ct < 4; ++ct) {
        short8 bv = *(const short8*)&Vl[(16 * ct + q) * 264 + ks * 32 + g * 8];
        o[ct] = MFMA16(ap, bv, o[ct]);
      }
    }

    // final row-sum: fold g-partials (row q), then fetch row 4g+jr's sum
    lsum += __shfl_xor(lsum, 16);
    lsum += __shfl_xor(lsum, 32);
    float linv[4];
#pragma unroll
    for (int jr = 0; jr < 4; ++jr) linv[jr] = 1.0f / __shfl(lsum, 4 * g + jr);

    const long rowbase = (long)b * 256 + 16 * t;
#pragma unroll
    for (int jr = 0; jr < 4; ++jr) {
#pragma unroll
      for (int ct = 0; ct < 4; ++ct) {
        out[(rowbase + 4 * g + jr) * 64 + 16 * ct + q] = o[ct][jr] * linv[jr];
      }
    }
  }
}

// ---------------------------------------------------------------------------
extern "C" void kernel_launch(void* const* d_in, const int* in_sizes, int n_in,
                              void* d_out, int out_size, void* d_ws, size_t ws_size,
                              hipStream_t stream) {
  const float* x  = (const float*)d_in[0];
  const float* Wq = (const float*)d_in[1];
  const float* Wk = (const float*)d_in[2];
  const float* Wv = (const float*)d_in[3];
  float* out = (float*)d_out;

  unsigned short* W3t = (unsigned short*)d_ws;  // 147,456 B

  hipFuncSetAttribute((const void*)fused_kernel,
                      hipFuncAttributeMaxDynamicSharedMemorySize, 147456);

  wconv_kernel<<<72, 128, 0, stream>>>(Wq, Wk, Wv, W3t);
  fused_kernel<<<256, 512, 147456, stream>>>(x, W3t, out);
}